// Round 2
// baseline (593.669 us; speedup 1.0000x reference)
//
#include <hip/hip_runtime.h>

// Problem constants
#define BB 16
#define NL 256
#define RR 24
#define LL 32
#define NN (NL*NL)        // 65536
#define BNN (BB*NN)       // 1048576
#define TT 64             // FW tile
#define NBLK 4            // 256/64

// Output layout (FLOAT32 elements), reference return order:
// total_demand_time[16], total_route_time[16], trips_at_transfers[16][4],
// total_demand[16], unserved[16], total_transfers[16], trip_times[16*256*256], n_disconnected[16]
#define O_TDT 0
#define O_RT  16
#define O_TAT 32
#define O_TD  96
#define O_UNS 112
#define O_TTR 128
#define O_TT  144
#define O_ND  1048720

static __device__ __forceinline__ void atomicMinF(float* a, float v){
    // valid for non-negative floats (incl. +inf): IEEE bits compare like uints
    atomicMin((unsigned int*)a, __float_as_uint(v));
}

// ---------------- init: dist = INF, accumulators = 0 ----------------
__global__ void k_init(float* __restrict__ dist, float* __restrict__ acc){
    int idx = blockIdx.x*256 + threadIdx.x;
    dist[idx] = __builtin_huge_valf();
    if (idx < 256) acc[idx] = 0.f;
}

// ---------------- route edges: one wave per (b,r) ----------------
__global__ void k_routes(const float* __restrict__ dtm, const int* __restrict__ routes,
                         float* __restrict__ dist, float* __restrict__ acc){
    int br = blockIdx.x; int b = br / RR, r = br % RR;
    int lane = threadIdx.x;
    __shared__ int   s[LL];
    __shared__ float lf[LL], lr[LL], cf[LL], cr[LL];
    if (lane < LL) s[lane] = routes[(b*RR + r)*LL + lane];
    __syncthreads();
    if (lane < LL-1){
        int a0 = s[lane], a1 = s[lane+1];
        const float* dt = dtm + b*NN;
        lf[lane] = dt[a0*NL + a1] + 60.0f;   // MEAN_STOP_TIME_S
        lr[lane] = dt[a1*NL + a0] + 60.0f;
    }
    __syncthreads();
    if (lane == 0){
        // sequential cumsum to match reference (np.cumsum) rounding
        float af = 0.f, ar = 0.f;
        cf[0] = 0.f; cr[0] = 0.f;
        for (int l = 0; l < LL-1; l++){
            af += lf[l]; ar += lr[l];
            cf[l+1] = af; cr[l+1] = ar;
        }
        atomicAdd(&acc[b*16 + 1], af + ar);  // total_route_time
    }
    __syncthreads();
    for (int p = lane; p < LL*LL; p += 64){
        int i = p >> 5, j = p & 31;
        if (j > i){
            atomicMinF(&dist[b*NN + s[i]*NL + s[j]], cf[j] - cf[i]); // fwd
            atomicMinF(&dist[b*NN + s[j]*NL + s[i]], cr[j] - cr[i]); // rev (symmetric)
        }
    }
}

// ---------------- FW init: diag=0, hops = finite&offdiag ? 1 : 0 ----------------
__global__ void k_fwinit(float* __restrict__ dist, float* __restrict__ hops){
    int idx = blockIdx.x*256 + threadIdx.x;
    int ij = idx & (NN-1);
    int i = ij >> 8, j = ij & 255;
    float d = dist[idx];
    if (i == j) d = 0.f;
    hops[idx] = (i != j && d < 1e37f) ? 1.f : 0.f;
    dist[idx] = d;
}

// ---------------- FW phase 1: diagonal tile ----------------
__global__ __launch_bounds__(256) void k_fw_diag(float* __restrict__ dist, float* __restrict__ hops, int kb){
    int b = blockIdx.x;
    int t = threadIdx.x, ty = t >> 4, tx = t & 15;
    int r0 = ty*4, c0 = tx*4;
    float* Dg = dist + b*NN + kb*TT*(NL+1);
    float* Hg = hops + b*NN + kb*TT*(NL+1);
    float d[4][4], h[4][4];
    #pragma unroll
    for (int ii = 0; ii < 4; ii++){
        float4 v = *(float4*)(Dg + (r0+ii)*NL + c0);
        float4 w = *(float4*)(Hg + (r0+ii)*NL + c0);
        d[ii][0]=v.x; d[ii][1]=v.y; d[ii][2]=v.z; d[ii][3]=v.w;
        h[ii][0]=w.x; h[ii][1]=w.y; h[ii][2]=w.z; h[ii][3]=w.w;
    }
    __shared__ float rD[2][TT], rH[2][TT], cD[2][TT], cH[2][TT];
    if (ty == 0){
        #pragma unroll
        for (int jj=0;jj<4;jj++){ rD[0][c0+jj]=d[0][jj]; rH[0][c0+jj]=h[0][jj]; }
    }
    if (tx == 0){
        #pragma unroll
        for (int ii=0;ii<4;ii++){ cD[0][r0+ii]=d[ii][0]; cH[0][r0+ii]=h[ii][0]; }
    }
    for (int k = 0; k < TT; k++){
        __syncthreads();
        int bf = k & 1;
        float4 rdv = *(float4*)&rD[bf][c0];
        float4 rhv = *(float4*)&rH[bf][c0];
        float4 cdv = *(float4*)&cD[bf][r0];
        float4 chv = *(float4*)&cH[bf][r0];
        float rd[4] = {rdv.x,rdv.y,rdv.z,rdv.w}, rh[4] = {rhv.x,rhv.y,rhv.z,rhv.w};
        float cd[4] = {cdv.x,cdv.y,cdv.z,cdv.w}, ch[4] = {chv.x,chv.y,chv.z,chv.w};
        #pragma unroll
        for (int ii=0;ii<4;ii++)
        #pragma unroll
        for (int jj=0;jj<4;jj++){
            float alt = cd[ii] + rd[jj];
            if (alt < d[ii][jj]){ d[ii][jj] = alt; h[ii][jj] = ch[ii] + rh[jj]; }
        }
        if (k < TT-1){
            int kn = k+1, nb = bf^1;
            if ((kn>>2) == ty){ int ii = kn & 3;
                #pragma unroll
                for (int jj=0;jj<4;jj++){ rD[nb][c0+jj]=d[ii][jj]; rH[nb][c0+jj]=h[ii][jj]; } }
            if ((kn>>2) == tx){ int jj = kn & 3;
                #pragma unroll
                for (int ii=0;ii<4;ii++){ cD[nb][r0+ii]=d[ii][jj]; cH[nb][r0+ii]=h[ii][jj]; } }
        }
    }
    #pragma unroll
    for (int ii = 0; ii < 4; ii++){
        *(float4*)(Dg + (r0+ii)*NL + c0) = make_float4(d[ii][0],d[ii][1],d[ii][2],d[ii][3]);
        *(float4*)(Hg + (r0+ii)*NL + c0) = make_float4(h[ii][0],h[ii][1],h[ii][2],h[ii][3]);
    }
}

// ---------------- FW phase 2: row tiles (kb,j) and col tiles (i,kb) ----------------
__global__ __launch_bounds__(256) void k_fw_p2(float* __restrict__ dist, float* __restrict__ hops, int kb){
    int b = blockIdx.y;
    int m = blockIdx.x;            // 0..5
    bool isRow = (m < 3);
    int o  = isRow ? m : m-3;
    int ob = o + (o >= kb ? 1 : 0);
    int ti = isRow ? kb : ob;
    int tj = isRow ? ob : kb;
    int t = threadIdx.x, ty = t >> 4, tx = t & 15;
    int r0 = ty*4, c0 = tx*4;
    float* Dg = dist + b*NN + ti*TT*NL + tj*TT;
    float* Hg = hops + b*NN + ti*TT*NL + tj*TT;
    const float* Ag  = dist + b*NN + kb*TT*(NL+1);
    const float* AHg = hops + b*NN + kb*TT*(NL+1);
    __shared__ float SD[TT][TT], SH[TT][TT];
    __shared__ float pD[2][TT], pH[2][TT];
    float d[4][4], h[4][4];
    #pragma unroll
    for (int ii = 0; ii < 4; ii++){
        float4 v = *(float4*)(Dg + (r0+ii)*NL + c0);
        float4 w = *(float4*)(Hg + (r0+ii)*NL + c0);
        d[ii][0]=v.x; d[ii][1]=v.y; d[ii][2]=v.z; d[ii][3]=v.w;
        h[ii][0]=w.x; h[ii][1]=w.y; h[ii][2]=w.z; h[ii][3]=w.w;
        float4 a = *(const float4*)(Ag  + (r0+ii)*NL + c0);
        float4 q = *(const float4*)(AHg + (r0+ii)*NL + c0);
        if (isRow){ // transpose A: SD[col][row] so A[i][k] reads are contiguous b128
            SD[c0+0][r0+ii]=a.x; SD[c0+1][r0+ii]=a.y; SD[c0+2][r0+ii]=a.z; SD[c0+3][r0+ii]=a.w;
            SH[c0+0][r0+ii]=q.x; SH[c0+1][r0+ii]=q.y; SH[c0+2][r0+ii]=q.z; SH[c0+3][r0+ii]=q.w;
        } else {
            *(float4*)&SD[r0+ii][c0] = a;
            *(float4*)&SH[r0+ii][c0] = q;
        }
    }
    if (isRow){
        if (ty == 0){
            #pragma unroll
            for (int jj=0;jj<4;jj++){ pD[0][c0+jj]=d[0][jj]; pH[0][c0+jj]=h[0][jj]; }
        }
    } else {
        if (tx == 0){
            #pragma unroll
            for (int ii=0;ii<4;ii++){ pD[0][r0+ii]=d[ii][0]; pH[0][r0+ii]=h[ii][0]; }
        }
    }
    for (int k = 0; k < TT; k++){
        __syncthreads();
        int bf = k & 1;
        if (isRow){
            float4 av = *(float4*)&SD[k][r0];   // A[i][k]
            float4 aq = *(float4*)&SH[k][r0];
            float4 pv = *(float4*)&pD[bf][c0];  // C[k][j]
            float4 pq = *(float4*)&pH[bf][c0];
            float a[4]={av.x,av.y,av.z,av.w}, ah[4]={aq.x,aq.y,aq.z,aq.w};
            float p[4]={pv.x,pv.y,pv.z,pv.w}, ph[4]={pq.x,pq.y,pq.z,pq.w};
            #pragma unroll
            for (int ii=0;ii<4;ii++)
            #pragma unroll
            for (int jj=0;jj<4;jj++){
                float alt = a[ii] + p[jj];
                if (alt < d[ii][jj]){ d[ii][jj]=alt; h[ii][jj]=ah[ii]+ph[jj]; }
            }
            if (k < TT-1){
                int kn = k+1, nb = bf^1;
                if ((kn>>2) == ty){ int ii = kn & 3;
                    #pragma unroll
                    for (int jj=0;jj<4;jj++){ pD[nb][c0+jj]=d[ii][jj]; pH[nb][c0+jj]=h[ii][jj]; } }
            }
        } else {
            float4 bv = *(float4*)&SD[k][c0];   // B[k][j]
            float4 bq = *(float4*)&SH[k][c0];
            float4 pv = *(float4*)&pD[bf][r0];  // C[i][k]
            float4 pq = *(float4*)&pH[bf][r0];
            float bb_[4]={bv.x,bv.y,bv.z,bv.w}, bh[4]={bq.x,bq.y,bq.z,bq.w};
            float p[4]={pv.x,pv.y,pv.z,pv.w},   ph[4]={pq.x,pq.y,pq.z,pq.w};
            #pragma unroll
            for (int ii=0;ii<4;ii++)
            #pragma unroll
            for (int jj=0;jj<4;jj++){
                float alt = p[ii] + bb_[jj];
                if (alt < d[ii][jj]){ d[ii][jj]=alt; h[ii][jj]=ph[ii]+bh[jj]; }
            }
            if (k < TT-1){
                int kn = k+1, nb = bf^1;
                if ((kn>>2) == tx){ int jj = kn & 3;
                    #pragma unroll
                    for (int ii=0;ii<4;ii++){ pD[nb][r0+ii]=d[ii][jj]; pH[nb][r0+ii]=h[ii][jj]; } }
            }
        }
    }
    #pragma unroll
    for (int ii = 0; ii < 4; ii++){
        *(float4*)(Dg + (r0+ii)*NL + c0) = make_float4(d[ii][0],d[ii][1],d[ii][2],d[ii][3]);
        *(float4*)(Hg + (r0+ii)*NL + c0) = make_float4(h[ii][0],h[ii][1],h[ii][2],h[ii][3]);
    }
}

// ---------------- FW phase 3: independent tiles, barrier-free k-loop ----------------
__global__ __launch_bounds__(256) void k_fw_p3(float* __restrict__ dist, float* __restrict__ hops, int kb){
    int b = blockIdx.y;
    int m = blockIdx.x;            // 0..8
    int pi = m/3, pj = m%3;
    int ib = pi + (pi >= kb ? 1 : 0);
    int jb = pj + (pj >= kb ? 1 : 0);
    int t = threadIdx.x, ty = t >> 4, tx = t & 15;
    int r0 = ty*4, c0 = tx*4;
    float* Dg = dist + b*NN + ib*TT*NL + jb*TT;
    float* Hg = hops + b*NN + ib*TT*NL + jb*TT;
    const float* Ag  = dist + b*NN + ib*TT*NL + kb*TT;   // col-phase tile (ib,kb)
    const float* AHg = hops + b*NN + ib*TT*NL + kb*TT;
    const float* Bg  = dist + b*NN + kb*TT*NL + jb*TT;   // row-phase tile (kb,jb)
    const float* BHg = hops + b*NN + kb*TT*NL + jb*TT;
    __shared__ float AtD[TT][TT], AtH[TT][TT], BD[TT][TT], BH[TT][TT]; // 64 KB
    float d[4][4], h[4][4];
    #pragma unroll
    for (int ii = 0; ii < 4; ii++){
        float4 v = *(float4*)(Dg + (r0+ii)*NL + c0);
        float4 w = *(float4*)(Hg + (r0+ii)*NL + c0);
        d[ii][0]=v.x; d[ii][1]=v.y; d[ii][2]=v.z; d[ii][3]=v.w;
        h[ii][0]=w.x; h[ii][1]=w.y; h[ii][2]=w.z; h[ii][3]=w.w;
        float4 a = *(const float4*)(Ag  + (r0+ii)*NL + c0);
        float4 q = *(const float4*)(AHg + (r0+ii)*NL + c0);
        AtD[c0+0][r0+ii]=a.x; AtD[c0+1][r0+ii]=a.y; AtD[c0+2][r0+ii]=a.z; AtD[c0+3][r0+ii]=a.w;
        AtH[c0+0][r0+ii]=q.x; AtH[c0+1][r0+ii]=q.y; AtH[c0+2][r0+ii]=q.z; AtH[c0+3][r0+ii]=q.w;
        *(float4*)&BD[r0+ii][c0] = *(const float4*)(Bg  + (r0+ii)*NL + c0);
        *(float4*)&BH[r0+ii][c0] = *(const float4*)(BHg + (r0+ii)*NL + c0);
    }
    __syncthreads();
    #pragma unroll 4
    for (int k = 0; k < TT; k++){
        float4 av = *(float4*)&AtD[k][r0];   // A[i][k]
        float4 aq = *(float4*)&AtH[k][r0];
        float4 bv = *(float4*)&BD[k][c0];    // B[k][j]
        float4 bq = *(float4*)&BH[k][c0];
        float a[4]={av.x,av.y,av.z,av.w}, ah[4]={aq.x,aq.y,aq.z,aq.w};
        float bb_[4]={bv.x,bv.y,bv.z,bv.w}, bh[4]={bq.x,bq.y,bq.z,bq.w};
        #pragma unroll
        for (int ii=0;ii<4;ii++)
        #pragma unroll
        for (int jj=0;jj<4;jj++){
            float alt = a[ii] + bb_[jj];
            if (alt < d[ii][jj]){ d[ii][jj]=alt; h[ii][jj]=ah[ii]+bh[jj]; }
        }
    }
    #pragma unroll
    for (int ii = 0; ii < 4; ii++){
        *(float4*)(Dg + (r0+ii)*NL + c0) = make_float4(d[ii][0],d[ii][1],d[ii][2],d[ii][3]);
        *(float4*)(Hg + (r0+ii)*NL + c0) = make_float4(h[ii][0],h[ii][1],h[ii][2],h[ii][3]);
    }
}

// ---------------- epilogue: trip_times + per-batch reductions ----------------
__global__ __launch_bounds__(256) void k_epi(const float* __restrict__ dist,
        const float* __restrict__ hops, const float* __restrict__ demand,
        float* __restrict__ out, float* __restrict__ acc){
    int b = blockIdx.y;
    int base = b*NN + blockIdx.x*1024 + threadIdx.x;
    float s0=0,s1=0,s2=0,s3=0,s4=0,s5=0,s6=0,s7=0,s8=0;
    #pragma unroll
    for (int u = 0; u < 4; u++){
        int idx = base + u*256;
        float d = dist[idx], h = hops[idx], dm = demand[idx];
        bool np = !(d < 1e37f);
        float pl = np ? 0.f : h + 1.f;
        float tr = (pl == 0.f) ? 0.f : pl - 2.f;
        float tt = np ? 0.f : d + tr*300.f;   // AVG_TRANSFER_WAIT_TIME_S
        out[O_TT + idx] = tt;
        s0 += dm*tt;
        s1 += dm*tr;
        s2 += np ? dm : 0.f;
        s3 += dm;
        s4 += (np && dm > 0.f) ? 1.f : 0.f;
        s5 += (tr == 0.f) ? dm : 0.f;
        s6 += (tr == 1.f) ? dm : 0.f;
        s7 += (tr == 2.f) ? dm : 0.f;
        s8 += (tr > 2.f) ? dm : 0.f;
    }
    #define RED(x) { x += __shfl_down(x,32); x += __shfl_down(x,16); x += __shfl_down(x,8); \
                     x += __shfl_down(x,4);  x += __shfl_down(x,2);  x += __shfl_down(x,1); }
    RED(s0) RED(s1) RED(s2) RED(s3) RED(s4) RED(s5) RED(s6) RED(s7) RED(s8)
    __shared__ float red[4][9];
    int w = threadIdx.x >> 6;
    if ((threadIdx.x & 63) == 0){
        red[w][0]=s0; red[w][1]=s1; red[w][2]=s2; red[w][3]=s3; red[w][4]=s4;
        red[w][5]=s5; red[w][6]=s6; red[w][7]=s7; red[w][8]=s8;
    }
    __syncthreads();
    if (threadIdx.x < 9){
        float v = red[0][threadIdx.x] + red[1][threadIdx.x]
                + red[2][threadIdx.x] + red[3][threadIdx.x];
        // acc slots: 0 tdt, 1 rt(from k_routes), 2 ttrans, 3 uns, 4 tdem, 5 ndis, 6 b0, 7 b1, 8 b2, 9 bun
        int slot = (threadIdx.x == 0) ? 0 : threadIdx.x + 1;
        atomicAdd(&acc[b*16 + slot], v);
    }
}

// ---------------- finalize scalar outputs ----------------
__global__ void k_final(const float* __restrict__ acc, float* __restrict__ out){
    int b = threadIdx.x;
    if (b < BB){
        const float* a = acc + b*16;
        out[O_TDT + b] = a[0];
        out[O_RT  + b] = a[1];
        out[O_TAT + 4*b + 0] = a[6];
        out[O_TAT + 4*b + 1] = a[7];
        out[O_TAT + 4*b + 2] = a[8];
        out[O_TAT + 4*b + 3] = a[9] + a[3];
        out[O_TD  + b] = a[4];
        out[O_UNS + b] = a[3];
        out[O_TTR + b] = a[2];
        out[O_ND  + b] = a[5];
    }
}

extern "C" void kernel_launch(void* const* d_in, const int* in_sizes, int n_in,
                              void* d_out, int out_size, void* d_ws, size_t ws_size,
                              hipStream_t stream){
    (void)in_sizes; (void)n_in; (void)out_size; (void)ws_size;
    const float* dtm    = (const float*)d_in[0];
    const float* demand = (const float*)d_in[1];
    const int*   routes = (const int*)d_in[2];
    float* out  = (float*)d_out;
    float* dist = (float*)d_ws;           // BNN floats
    float* hops = dist + BNN;             // BNN floats
    float* acc  = hops + BNN;             // 256 floats (16 batches x 16 slots)

    k_init  <<<BNN/256, 256, 0, stream>>>(dist, acc);
    k_routes<<<BB*RR,    64, 0, stream>>>(dtm, routes, dist, acc);
    k_fwinit<<<BNN/256, 256, 0, stream>>>(dist, hops);
    for (int kb = 0; kb < NBLK; kb++){
        k_fw_diag<<<BB,          256, 0, stream>>>(dist, hops, kb);
        k_fw_p2  <<<dim3(6,BB),  256, 0, stream>>>(dist, hops, kb);
        k_fw_p3  <<<dim3(9,BB),  256, 0, stream>>>(dist, hops, kb);
    }
    k_epi  <<<dim3(64,BB), 256, 0, stream>>>(dist, hops, demand, out, acc);
    k_final<<<1, 64, 0, stream>>>(acc, out);
}

// Round 3
// 388.072 us; speedup vs baseline: 1.5298x; 1.5298x over previous
//
#include <hip/hip_runtime.h>

// Problem constants
#define BB 16
#define NL 256
#define RR 24
#define LL 32
#define NN (NL*NL)        // 65536
#define BNN (BB*NN)       // 1048576
#define TT 64             // FW tile
#define NBLK 4            // 256/64

// Output layout (float32), reference return order.
#define O_TDT 0
#define O_RT  16
#define O_TAT 32
#define O_TD  96
#define O_UNS 112
#define O_TTR 128
#define O_TT  144
#define O_ND  1048720

static __device__ __forceinline__ void atomicMinF(float* a, float v){
    atomicMin((unsigned int*)a, __float_as_uint(v));  // ok for non-negative floats
}

// ---------------- init: dist = INF, accumulators = 0 ----------------
__global__ void k_init(float* __restrict__ dist, float* __restrict__ acc){
    int idx = blockIdx.x*256 + threadIdx.x;
    dist[idx] = __builtin_huge_valf();
    if (idx < 256) acc[idx] = 0.f;
}

// ---------------- route edges: one wave per (b,r) ----------------
__global__ void k_routes(const float* __restrict__ dtm, const int* __restrict__ routes,
                         float* __restrict__ dist, float* __restrict__ acc){
    int br = blockIdx.x; int b = br / RR, r = br % RR;
    int lane = threadIdx.x;
    __shared__ int   s[LL];
    __shared__ float lf[LL], lr[LL], cf[LL], cr[LL];
    if (lane < LL) s[lane] = routes[(b*RR + r)*LL + lane];
    __syncthreads();
    if (lane < LL-1){
        int a0 = s[lane], a1 = s[lane+1];
        const float* dt = dtm + b*NN;
        lf[lane] = dt[a0*NL + a1] + 60.0f;   // MEAN_STOP_TIME_S
        lr[lane] = dt[a1*NL + a0] + 60.0f;
    }
    __syncthreads();
    if (lane == 0){
        float af = 0.f, ar = 0.f;
        cf[0] = 0.f; cr[0] = 0.f;
        for (int l = 0; l < LL-1; l++){
            af += lf[l]; ar += lr[l];
            cf[l+1] = af; cr[l+1] = ar;
        }
        atomicAdd(&acc[b*16 + 1], af + ar);  // total_route_time
    }
    __syncthreads();
    for (int p = lane; p < LL*LL; p += 64){
        int i = p >> 5, j = p & 31;
        if (j > i){
            atomicMinF(&dist[b*NN + s[i]*NL + s[j]], cf[j] - cf[i]); // fwd
            atomicMinF(&dist[b*NN + s[j]*NL + s[i]], cr[j] - cr[i]); // rev
        }
    }
}

// ---------------- FW init: diag=0, hops = finite&offdiag ? 1 : 0 ----------------
__global__ void k_fwinit(float* __restrict__ dist, float* __restrict__ hops){
    int idx = blockIdx.x*256 + threadIdx.x;
    int ij = idx & (NN-1);
    int i = ij >> 8, j = ij & 255;
    float d = dist[idx];
    if (i == j) d = 0.f;
    hops[idx] = (i != j && d < 1e37f) ? 1.f : 0.f;
    dist[idx] = d;
}

// ---------------- FW phase 1: diagonal tile (serial in k, barrier per k) ----------------
__global__ __launch_bounds__(256) void k_fw_diag(float* __restrict__ dist, float* __restrict__ hops, int kb){
    int b = blockIdx.x;
    int t = threadIdx.x, ty = t >> 4, tx = t & 15;
    int r0 = ty*4, c0 = tx*4;
    float* Dg = dist + b*NN + kb*TT*(NL+1);
    float* Hg = hops + b*NN + kb*TT*(NL+1);
    float d[4][4], h[4][4];
    #pragma unroll
    for (int ii = 0; ii < 4; ii++){
        float4 v = *(float4*)(Dg + (r0+ii)*NL + c0);
        float4 w = *(float4*)(Hg + (r0+ii)*NL + c0);
        d[ii][0]=v.x; d[ii][1]=v.y; d[ii][2]=v.z; d[ii][3]=v.w;
        h[ii][0]=w.x; h[ii][1]=w.y; h[ii][2]=w.z; h[ii][3]=w.w;
    }
    __shared__ float rD[2][TT], rH[2][TT], cD[2][TT], cH[2][TT];
    if (ty == 0){
        #pragma unroll
        for (int jj=0;jj<4;jj++){ rD[0][c0+jj]=d[0][jj]; rH[0][c0+jj]=h[0][jj]; }
    }
    if (tx == 0){
        #pragma unroll
        for (int ii=0;ii<4;ii++){ cD[0][r0+ii]=d[ii][0]; cH[0][r0+ii]=h[ii][0]; }
    }
    for (int k = 0; k < TT; k++){
        __syncthreads();
        int bf = k & 1;
        float4 rdv = *(float4*)&rD[bf][c0];
        float4 rhv = *(float4*)&rH[bf][c0];
        float4 cdv = *(float4*)&cD[bf][r0];
        float4 chv = *(float4*)&cH[bf][r0];
        float rd[4] = {rdv.x,rdv.y,rdv.z,rdv.w}, rh[4] = {rhv.x,rhv.y,rhv.z,rhv.w};
        float cd[4] = {cdv.x,cdv.y,cdv.z,cdv.w}, ch[4] = {chv.x,chv.y,chv.z,chv.w};
        #pragma unroll
        for (int ii=0;ii<4;ii++)
        #pragma unroll
        for (int jj=0;jj<4;jj++){
            float alt = cd[ii] + rd[jj];
            if (alt < d[ii][jj]){ d[ii][jj] = alt; h[ii][jj] = ch[ii] + rh[jj]; }
        }
        if (k < TT-1){
            int kn = k+1, nb = bf^1;
            if ((kn>>2) == ty){ int ii = kn & 3;
                #pragma unroll
                for (int jj=0;jj<4;jj++){ rD[nb][c0+jj]=d[ii][jj]; rH[nb][c0+jj]=h[ii][jj]; } }
            if ((kn>>2) == tx){ int jj = kn & 3;
                #pragma unroll
                for (int ii=0;ii<4;ii++){ cD[nb][r0+ii]=d[ii][jj]; cH[nb][r0+ii]=h[ii][jj]; } }
        }
    }
    #pragma unroll
    for (int ii = 0; ii < 4; ii++){
        *(float4*)(Dg + (r0+ii)*NL + c0) = make_float4(d[ii][0],d[ii][1],d[ii][2],d[ii][3]);
        *(float4*)(Hg + (r0+ii)*NL + c0) = make_float4(h[ii][0],h[ii][1],h[ii][2],h[ii][3]);
    }
}

// ---------------- FW phases 2+3 unified: min-plus product, barrier-free k-loop ------
// dst tile (ti,tj); A-operand tile = (ti,kb); B-operand tile = (kb,tj).
// phase2 (gridDim.x=6): dst = row tiles (kb,ob) and col tiles (ob,kb).
//   row: A=(kb,kb)=closed diag, B=dst(C0). col: A=dst(C0), B=diag. Valid because
//   diag is transitively closed => product form == in-place FW loop (see journal).
// phase3 (gridDim.x=9): dst=(ib,jb), A=(ib,kb) from p2-col, B=(kb,jb) from p2-row.
__global__ __launch_bounds__(256) void k_fw_mp(float* __restrict__ dist, float* __restrict__ hops,
                                               int kb, int phase){
    int b = blockIdx.y;
    int m = blockIdx.x;
    int ti, tj;
    if (phase == 2){
        bool isRow = (m < 3);
        int o  = isRow ? m : m-3;
        int ob = o + (o >= kb ? 1 : 0);
        ti = isRow ? kb : ob;
        tj = isRow ? ob : kb;
    } else {
        int pi = m/3, pj = m%3;
        ti = pi + (pi >= kb ? 1 : 0);
        tj = pj + (pj >= kb ? 1 : 0);
    }
    int t = threadIdx.x, ty = t >> 4, tx = t & 15;
    int r0 = ty*4, c0 = tx*4;
    float* Dg = dist + b*NN + ti*TT*NL + tj*TT;
    float* Hg = hops + b*NN + ti*TT*NL + tj*TT;
    const float* Ag  = dist + b*NN + ti*TT*NL + kb*TT;
    const float* AHg = hops + b*NN + ti*TT*NL + kb*TT;
    const float* Bg  = dist + b*NN + kb*TT*NL + tj*TT;
    const float* BHg = hops + b*NN + kb*TT*NL + tj*TT;
    __shared__ float AtD[TT][TT], AtH[TT][TT], BD[TT][TT], BH[TT][TT]; // 64 KB
    float d[4][4], h[4][4];
    #pragma unroll
    for (int ii = 0; ii < 4; ii++){
        float4 v = *(float4*)(Dg + (r0+ii)*NL + c0);
        float4 w = *(float4*)(Hg + (r0+ii)*NL + c0);
        d[ii][0]=v.x; d[ii][1]=v.y; d[ii][2]=v.z; d[ii][3]=v.w;
        h[ii][0]=w.x; h[ii][1]=w.y; h[ii][2]=w.z; h[ii][3]=w.w;
        float4 a = *(const float4*)(Ag  + (r0+ii)*NL + c0);
        float4 q = *(const float4*)(AHg + (r0+ii)*NL + c0);
        AtD[c0+0][r0+ii]=a.x; AtD[c0+1][r0+ii]=a.y; AtD[c0+2][r0+ii]=a.z; AtD[c0+3][r0+ii]=a.w;
        AtH[c0+0][r0+ii]=q.x; AtH[c0+1][r0+ii]=q.y; AtH[c0+2][r0+ii]=q.z; AtH[c0+3][r0+ii]=q.w;
        *(float4*)&BD[r0+ii][c0] = *(const float4*)(Bg  + (r0+ii)*NL + c0);
        *(float4*)&BH[r0+ii][c0] = *(const float4*)(BHg + (r0+ii)*NL + c0);
    }
    __syncthreads();
    #pragma unroll 4
    for (int k = 0; k < TT; k++){
        float4 av = *(float4*)&AtD[k][r0];   // A[i][k], i = r0..r0+3
        float4 aq = *(float4*)&AtH[k][r0];
        float4 bv = *(float4*)&BD[k][c0];    // B[k][j], j = c0..c0+3
        float4 bq = *(float4*)&BH[k][c0];
        float a[4]={av.x,av.y,av.z,av.w}, ah[4]={aq.x,aq.y,aq.z,aq.w};
        float bb_[4]={bv.x,bv.y,bv.z,bv.w}, bh[4]={bq.x,bq.y,bq.z,bq.w};
        #pragma unroll
        for (int ii=0;ii<4;ii++)
        #pragma unroll
        for (int jj=0;jj<4;jj++){
            float alt = a[ii] + bb_[jj];
            if (alt < d[ii][jj]){ d[ii][jj]=alt; h[ii][jj]=ah[ii]+bh[jj]; }
        }
    }
    #pragma unroll
    for (int ii = 0; ii < 4; ii++){
        *(float4*)(Dg + (r0+ii)*NL + c0) = make_float4(d[ii][0],d[ii][1],d[ii][2],d[ii][3]);
        *(float4*)(Hg + (r0+ii)*NL + c0) = make_float4(h[ii][0],h[ii][1],h[ii][2],h[ii][3]);
    }
}

// ---------------- epilogue: trip_times + per-batch reductions ----------------
__global__ __launch_bounds__(256) void k_epi(const float* __restrict__ dist,
        const float* __restrict__ hops, const float* __restrict__ demand,
        float* __restrict__ out, float* __restrict__ acc){
    int b = blockIdx.y;
    int base = b*NN + blockIdx.x*1024 + threadIdx.x;
    float s0=0,s1=0,s2=0,s3=0,s4=0,s5=0,s6=0,s7=0,s8=0;
    #pragma unroll
    for (int u = 0; u < 4; u++){
        int idx = base + u*256;
        float d = dist[idx], h = hops[idx], dm = demand[idx];
        bool np = !(d < 1e37f);
        float pl = np ? 0.f : h + 1.f;
        float tr = (pl == 0.f) ? 0.f : pl - 2.f;
        float tt = np ? 0.f : d + tr*300.f;   // AVG_TRANSFER_WAIT_TIME_S
        out[O_TT + idx] = tt;
        s0 += dm*tt;
        s1 += dm*tr;
        s2 += np ? dm : 0.f;
        s3 += dm;
        s4 += (np && dm > 0.f) ? 1.f : 0.f;
        s5 += (tr == 0.f) ? dm : 0.f;
        s6 += (tr == 1.f) ? dm : 0.f;
        s7 += (tr == 2.f) ? dm : 0.f;
        s8 += (tr > 2.f) ? dm : 0.f;
    }
    #define RED(x) { x += __shfl_down(x,32); x += __shfl_down(x,16); x += __shfl_down(x,8); \
                     x += __shfl_down(x,4);  x += __shfl_down(x,2);  x += __shfl_down(x,1); }
    RED(s0) RED(s1) RED(s2) RED(s3) RED(s4) RED(s5) RED(s6) RED(s7) RED(s8)
    __shared__ float red[4][9];
    int w = threadIdx.x >> 6;
    if ((threadIdx.x & 63) == 0){
        red[w][0]=s0; red[w][1]=s1; red[w][2]=s2; red[w][3]=s3; red[w][4]=s4;
        red[w][5]=s5; red[w][6]=s6; red[w][7]=s7; red[w][8]=s8;
    }
    __syncthreads();
    if (threadIdx.x < 9){
        float v = red[0][threadIdx.x] + red[1][threadIdx.x]
                + red[2][threadIdx.x] + red[3][threadIdx.x];
        // acc slots: 0 tdt, 1 rt, 2 ttrans, 3 uns, 4 tdem, 5 ndis, 6 b0, 7 b1, 8 b2, 9 bun
        int slot = (threadIdx.x == 0) ? 0 : threadIdx.x + 1;
        atomicAdd(&acc[b*16 + slot], v);
    }
}

// ---------------- finalize scalar outputs ----------------
__global__ void k_final(const float* __restrict__ acc, float* __restrict__ out){
    int b = threadIdx.x;
    if (b < BB){
        const float* a = acc + b*16;
        out[O_TDT + b] = a[0];
        out[O_RT  + b] = a[1];
        out[O_TAT + 4*b + 0] = a[6];
        out[O_TAT + 4*b + 1] = a[7];
        out[O_TAT + 4*b + 2] = a[8];
        out[O_TAT + 4*b + 3] = a[9] + a[3];
        out[O_TD  + b] = a[4];
        out[O_UNS + b] = a[3];
        out[O_TTR + b] = a[2];
        out[O_ND  + b] = a[5];
    }
}

extern "C" void kernel_launch(void* const* d_in, const int* in_sizes, int n_in,
                              void* d_out, int out_size, void* d_ws, size_t ws_size,
                              hipStream_t stream){
    (void)in_sizes; (void)n_in; (void)out_size; (void)ws_size;
    const float* dtm    = (const float*)d_in[0];
    const float* demand = (const float*)d_in[1];
    const int*   routes = (const int*)d_in[2];
    float* out  = (float*)d_out;
    float* dist = (float*)d_ws;           // BNN floats
    float* hops = dist + BNN;             // BNN floats
    float* acc  = hops + BNN;             // 256 floats

    k_init  <<<BNN/256, 256, 0, stream>>>(dist, acc);
    k_routes<<<BB*RR,    64, 0, stream>>>(dtm, routes, dist, acc);
    k_fwinit<<<BNN/256, 256, 0, stream>>>(dist, hops);
    for (int kb = 0; kb < NBLK; kb++){
        k_fw_diag<<<BB,         256, 0, stream>>>(dist, hops, kb);
        k_fw_mp  <<<dim3(6,BB), 256, 0, stream>>>(dist, hops, kb, 2);
        k_fw_mp  <<<dim3(9,BB), 256, 0, stream>>>(dist, hops, kb, 3);
    }
    k_epi  <<<dim3(64,BB), 256, 0, stream>>>(dist, hops, demand, out, acc);
    k_final<<<1, 64, 0, stream>>>(acc, out);
}

// Round 4
// 379.204 us; speedup vs baseline: 1.5656x; 1.0234x over previous
//
#include <hip/hip_runtime.h>

// Problem constants
#define BB 16
#define NL 256
#define RR 24
#define LL 32
#define NN (NL*NL)        // 65536
#define BNN (BB*NN)       // 1048576
#define TT 64             // FW tile
#define NBLK 4            // 256/64

// Output layout (float32), reference return order.
#define O_TDT 0
#define O_RT  16
#define O_TAT 32
#define O_TD  96
#define O_UNS 112
#define O_TTR 128
#define O_TT  144
#define O_ND  1048720

static __device__ __forceinline__ void atomicMinF(float* a, float v){
    atomicMin((unsigned int*)a, __float_as_uint(v));  // ok for non-negative floats
}

// ---------------- init: dist = INF, accumulators = 0 ----------------
__global__ void k_init(float* __restrict__ dist, float* __restrict__ acc){
    int idx = blockIdx.x*256 + threadIdx.x;
    dist[idx] = __builtin_huge_valf();
    if (idx < 256) acc[idx] = 0.f;
}

// ---------------- route edges: one wave per (b,r) ----------------
__global__ void k_routes(const float* __restrict__ dtm, const int* __restrict__ routes,
                         float* __restrict__ dist, float* __restrict__ acc){
    int br = blockIdx.x; int b = br / RR, r = br % RR;
    int lane = threadIdx.x;
    __shared__ int   s[LL];
    __shared__ float lf[LL], lr[LL], cf[LL], cr[LL];
    if (lane < LL) s[lane] = routes[(b*RR + r)*LL + lane];
    __syncthreads();
    if (lane < LL-1){
        int a0 = s[lane], a1 = s[lane+1];
        const float* dt = dtm + b*NN;
        lf[lane] = dt[a0*NL + a1] + 60.0f;   // MEAN_STOP_TIME_S
        lr[lane] = dt[a1*NL + a0] + 60.0f;
    }
    __syncthreads();
    if (lane == 0){
        float af = 0.f, ar = 0.f;
        cf[0] = 0.f; cr[0] = 0.f;
        for (int l = 0; l < LL-1; l++){
            af += lf[l]; ar += lr[l];
            cf[l+1] = af; cr[l+1] = ar;
        }
        atomicAdd(&acc[b*16 + 1], af + ar);  // total_route_time
    }
    __syncthreads();
    for (int p = lane; p < LL*LL; p += 64){
        int i = p >> 5, j = p & 31;
        if (j > i){
            atomicMinF(&dist[b*NN + s[i]*NL + s[j]], cf[j] - cf[i]); // fwd
            atomicMinF(&dist[b*NN + s[j]*NL + s[i]], cr[j] - cr[i]); // rev
        }
    }
}

// ---------------- FW init: diag=0, hops = finite&offdiag ? 1 : 0 ----------------
__global__ void k_fwinit(float* __restrict__ dist, float* __restrict__ hops){
    int idx = blockIdx.x*256 + threadIdx.x;
    int ij = idx & (NN-1);
    int i = ij >> 8, j = ij & 255;
    float d = dist[idx];
    if (i == j) d = 0.f;
    hops[idx] = (i != j && d < 1e37f) ? 1.f : 0.f;
    dist[idx] = d;
}

// ---------------- FW phase 1: hierarchical closure of the 64x64 diagonal tile ----
// Kleene recursion with sub-tile 16: per sub-round, p1' = in-wave shfl FW (no
// barriers), p2' = product-form strips (1 barrier), p3' = barrier-free 48x48.
__global__ __launch_bounds__(256) void k_fw_diag(float* __restrict__ dist, float* __restrict__ hops, int kb){
    int b = blockIdx.x;
    int t = threadIdx.x;
    __shared__ float D[TT][TT+1], H[TT][TT+1];
    float* Dg = dist + b*NN + kb*TT*(NL+1);
    float* Hg = hops + b*NN + kb*TT*(NL+1);
    // stage in (coalesced float4 global loads)
    #pragma unroll
    for (int u = 0; u < 4; u++){
        int fid = u*256 + t;               // float4 id 0..1023
        int row = fid >> 4, c4 = (fid & 15) * 4;
        float4 v = *(const float4*)(Dg + row*NL + c4);
        float4 w = *(const float4*)(Hg + row*NL + c4);
        D[row][c4+0]=v.x; D[row][c4+1]=v.y; D[row][c4+2]=v.z; D[row][c4+3]=v.w;
        H[row][c4+0]=w.x; H[row][c4+1]=w.y; H[row][c4+2]=w.z; H[row][c4+3]=w.w;
    }
    __syncthreads();
    int ty = t >> 4, tx = t & 15;
    for (int skb = 0; skb < 4; skb++){
        int s0 = skb*16;
        // ---- p1': wave 0 closes 16x16 diag sub-tile via shfl; element (i,j)
        // owned by lane (i<<2)|(j>>2), register j&3.
        if (t < 64){
            int i = t >> 2, jg = t & 3;
            float md[4], mh[4];
            #pragma unroll
            for (int c = 0; c < 4; c++){
                md[c] = D[s0+i][s0+4*jg+c];
                mh[c] = H[s0+i][s0+4*jg+c];
            }
            #pragma unroll
            for (int k = 0; k < 16; k++){
                float rd[4], rh[4];
                #pragma unroll
                for (int c = 0; c < 4; c++){
                    rd[c] = __shfl(md[c], (k<<2)|jg);   // row k at my 4 cols
                    rh[c] = __shfl(mh[c], (k<<2)|jg);
                }
                float cdv = __shfl(md[k&3], (i<<2)|(k>>2));  // col k at my row
                float chv = __shfl(mh[k&3], (i<<2)|(k>>2));
                #pragma unroll
                for (int c = 0; c < 4; c++){
                    float alt = cdv + rd[c];
                    if (alt < md[c]){ md[c] = alt; mh[c] = chv + rh[c]; }
                }
            }
            #pragma unroll
            for (int c = 0; c < 4; c++){
                D[s0+i][s0+4*jg+c] = md[c];
                H[s0+i][s0+4*jg+c] = mh[c];
            }
        }
        __syncthreads();
        // ---- p2': row strip (band rows x 48 off-band cols) and col strip
        // (48 off-band rows x band cols), product form vs closed sub-diag.
        float rsd[3], rsh[3], csd[3], csh[3];
        int gc[3], gr[3];
        #pragma unroll
        for (int e = 0; e < 3; e++){
            int c = tx*3 + e; gc[e] = (c < s0) ? c : c + 16;
            int r = ty*3 + e; gr[e] = (r < s0) ? r : r + 16;
            rsd[e] = D[s0+ty][gc[e]]; rsh[e] = H[s0+ty][gc[e]];
            csd[e] = D[gr[e]][s0+tx]; csh[e] = H[gr[e]][s0+tx];
        }
        #pragma unroll 4
        for (int k = 0; k < 16; k++){
            float ad = D[s0+ty][s0+k], ah = H[s0+ty][s0+k];   // A'[ty][k]
            float bd = D[s0+k][s0+tx], bh = H[s0+k][s0+tx];   // A'[k][tx]
            #pragma unroll
            for (int e = 0; e < 3; e++){
                float b0 = D[s0+k][gc[e]], b0h = H[s0+k][gc[e]];
                float alt = ad + b0;
                if (alt < rsd[e]){ rsd[e] = alt; rsh[e] = ah + b0h; }
                float c0 = D[gr[e]][s0+k], c0h = H[gr[e]][s0+k];
                float alt2 = c0 + bd;
                if (alt2 < csd[e]){ csd[e] = alt2; csh[e] = c0h + bh; }
            }
        }
        __syncthreads();   // all strip reads done before strip writes
        #pragma unroll
        for (int e = 0; e < 3; e++){
            D[s0+ty][gc[e]] = rsd[e]; H[s0+ty][gc[e]] = rsh[e];
            D[gr[e]][s0+tx] = csd[e]; H[gr[e]][s0+tx] = csh[e];
        }
        __syncthreads();
        // ---- p3': 48x48 remainder, 3x3 per thread, barrier-free k loop
        float dd[3][3], hh[3][3];
        #pragma unroll
        for (int e = 0; e < 3; e++)
        #pragma unroll
        for (int f = 0; f < 3; f++){
            dd[e][f] = D[gr[e]][gc[f]]; hh[e][f] = H[gr[e]][gc[f]];
        }
        #pragma unroll 4
        for (int k = 0; k < 16; k++){
            float ad[3], ah2[3], bd2[3], bh2[3];
            #pragma unroll
            for (int e = 0; e < 3; e++){ ad[e] = D[gr[e]][s0+k]; ah2[e] = H[gr[e]][s0+k]; }
            #pragma unroll
            for (int f = 0; f < 3; f++){ bd2[f] = D[s0+k][gc[f]]; bh2[f] = H[s0+k][gc[f]]; }
            #pragma unroll
            for (int e = 0; e < 3; e++)
            #pragma unroll
            for (int f = 0; f < 3; f++){
                float alt = ad[e] + bd2[f];
                if (alt < dd[e][f]){ dd[e][f] = alt; hh[e][f] = ah2[e] + bh2[f]; }
            }
        }
        #pragma unroll
        for (int e = 0; e < 3; e++)
        #pragma unroll
        for (int f = 0; f < 3; f++){
            D[gr[e]][gc[f]] = dd[e][f]; H[gr[e]][gc[f]] = hh[e][f];
        }
        __syncthreads();
    }
    // stage out
    #pragma unroll
    for (int u = 0; u < 4; u++){
        int fid = u*256 + t;
        int row = fid >> 4, c4 = (fid & 15) * 4;
        *(float4*)(Dg + row*NL + c4) = make_float4(D[row][c4+0],D[row][c4+1],D[row][c4+2],D[row][c4+3]);
        *(float4*)(Hg + row*NL + c4) = make_float4(H[row][c4+0],H[row][c4+1],H[row][c4+2],H[row][c4+3]);
    }
}

// ---------------- FW phases 2+3 unified: min-plus product, barrier-free k-loop ------
__global__ __launch_bounds__(256) void k_fw_mp(float* __restrict__ dist, float* __restrict__ hops,
                                               int kb, int phase){
    int b = blockIdx.y;
    int m = blockIdx.x;
    int ti, tj;
    if (phase == 2){
        bool isRow = (m < 3);
        int o  = isRow ? m : m-3;
        int ob = o + (o >= kb ? 1 : 0);
        ti = isRow ? kb : ob;
        tj = isRow ? ob : kb;
    } else {
        int pi = m/3, pj = m%3;
        ti = pi + (pi >= kb ? 1 : 0);
        tj = pj + (pj >= kb ? 1 : 0);
    }
    int t = threadIdx.x, ty = t >> 4, tx = t & 15;
    int r0 = ty*4, c0 = tx*4;
    float* Dg = dist + b*NN + ti*TT*NL + tj*TT;
    float* Hg = hops + b*NN + ti*TT*NL + tj*TT;
    const float* Ag  = dist + b*NN + ti*TT*NL + kb*TT;
    const float* AHg = hops + b*NN + ti*TT*NL + kb*TT;
    const float* Bg  = dist + b*NN + kb*TT*NL + tj*TT;
    const float* BHg = hops + b*NN + kb*TT*NL + tj*TT;
    __shared__ float AtD[TT][TT], AtH[TT][TT], BD[TT][TT], BH[TT][TT]; // 64 KB
    float d[4][4], h[4][4];
    #pragma unroll
    for (int ii = 0; ii < 4; ii++){
        float4 v = *(float4*)(Dg + (r0+ii)*NL + c0);
        float4 w = *(float4*)(Hg + (r0+ii)*NL + c0);
        d[ii][0]=v.x; d[ii][1]=v.y; d[ii][2]=v.z; d[ii][3]=v.w;
        h[ii][0]=w.x; h[ii][1]=w.y; h[ii][2]=w.z; h[ii][3]=w.w;
        float4 a = *(const float4*)(Ag  + (r0+ii)*NL + c0);
        float4 q = *(const float4*)(AHg + (r0+ii)*NL + c0);
        AtD[c0+0][r0+ii]=a.x; AtD[c0+1][r0+ii]=a.y; AtD[c0+2][r0+ii]=a.z; AtD[c0+3][r0+ii]=a.w;
        AtH[c0+0][r0+ii]=q.x; AtH[c0+1][r0+ii]=q.y; AtH[c0+2][r0+ii]=q.z; AtH[c0+3][r0+ii]=q.w;
        *(float4*)&BD[r0+ii][c0] = *(const float4*)(Bg  + (r0+ii)*NL + c0);
        *(float4*)&BH[r0+ii][c0] = *(const float4*)(BHg + (r0+ii)*NL + c0);
    }
    __syncthreads();
    #pragma unroll 4
    for (int k = 0; k < TT; k++){
        float4 av = *(float4*)&AtD[k][r0];
        float4 aq = *(float4*)&AtH[k][r0];
        float4 bv = *(float4*)&BD[k][c0];
        float4 bq = *(float4*)&BH[k][c0];
        float a[4]={av.x,av.y,av.z,av.w}, ah[4]={aq.x,aq.y,aq.z,aq.w};
        float bb_[4]={bv.x,bv.y,bv.z,bv.w}, bh[4]={bq.x,bq.y,bq.z,bq.w};
        #pragma unroll
        for (int ii=0;ii<4;ii++)
        #pragma unroll
        for (int jj=0;jj<4;jj++){
            float alt = a[ii] + bb_[jj];
            if (alt < d[ii][jj]){ d[ii][jj]=alt; h[ii][jj]=ah[ii]+bh[jj]; }
        }
    }
    #pragma unroll
    for (int ii = 0; ii < 4; ii++){
        *(float4*)(Dg + (r0+ii)*NL + c0) = make_float4(d[ii][0],d[ii][1],d[ii][2],d[ii][3]);
        *(float4*)(Hg + (r0+ii)*NL + c0) = make_float4(h[ii][0],h[ii][1],h[ii][2],h[ii][3]);
    }
}

// ---------------- epilogue: trip_times + per-batch reductions ----------------
__global__ __launch_bounds__(256) void k_epi(const float* __restrict__ dist,
        const float* __restrict__ hops, const float* __restrict__ demand,
        float* __restrict__ out, float* __restrict__ acc){
    int b = blockIdx.y;
    int base = b*NN + blockIdx.x*1024 + threadIdx.x;
    float s0=0,s1=0,s2=0,s3=0,s4=0,s5=0,s6=0,s7=0,s8=0;
    #pragma unroll
    for (int u = 0; u < 4; u++){
        int idx = base + u*256;
        float d = dist[idx], h = hops[idx], dm = demand[idx];
        bool np = !(d < 1e37f);
        float pl = np ? 0.f : h + 1.f;
        float tr = (pl == 0.f) ? 0.f : pl - 2.f;
        float tt = np ? 0.f : d + tr*300.f;
        out[O_TT + idx] = tt;
        s0 += dm*tt;
        s1 += dm*tr;
        s2 += np ? dm : 0.f;
        s3 += dm;
        s4 += (np && dm > 0.f) ? 1.f : 0.f;
        s5 += (tr == 0.f) ? dm : 0.f;
        s6 += (tr == 1.f) ? dm : 0.f;
        s7 += (tr == 2.f) ? dm : 0.f;
        s8 += (tr > 2.f) ? dm : 0.f;
    }
    #define RED(x) { x += __shfl_down(x,32); x += __shfl_down(x,16); x += __shfl_down(x,8); \
                     x += __shfl_down(x,4);  x += __shfl_down(x,2);  x += __shfl_down(x,1); }
    RED(s0) RED(s1) RED(s2) RED(s3) RED(s4) RED(s5) RED(s6) RED(s7) RED(s8)
    __shared__ float red[4][9];
    int w = threadIdx.x >> 6;
    if ((threadIdx.x & 63) == 0){
        red[w][0]=s0; red[w][1]=s1; red[w][2]=s2; red[w][3]=s3; red[w][4]=s4;
        red[w][5]=s5; red[w][6]=s6; red[w][7]=s7; red[w][8]=s8;
    }
    __syncthreads();
    if (threadIdx.x < 9){
        float v = red[0][threadIdx.x] + red[1][threadIdx.x]
                + red[2][threadIdx.x] + red[3][threadIdx.x];
        int slot = (threadIdx.x == 0) ? 0 : threadIdx.x + 1;
        atomicAdd(&acc[b*16 + slot], v);
    }
}

// ---------------- finalize scalar outputs ----------------
__global__ void k_final(const float* __restrict__ acc, float* __restrict__ out){
    int b = threadIdx.x;
    if (b < BB){
        const float* a = acc + b*16;
        out[O_TDT + b] = a[0];
        out[O_RT  + b] = a[1];
        out[O_TAT + 4*b + 0] = a[6];
        out[O_TAT + 4*b + 1] = a[7];
        out[O_TAT + 4*b + 2] = a[8];
        out[O_TAT + 4*b + 3] = a[9] + a[3];
        out[O_TD  + b] = a[4];
        out[O_UNS + b] = a[3];
        out[O_TTR + b] = a[2];
        out[O_ND  + b] = a[5];
    }
}

extern "C" void kernel_launch(void* const* d_in, const int* in_sizes, int n_in,
                              void* d_out, int out_size, void* d_ws, size_t ws_size,
                              hipStream_t stream){
    (void)in_sizes; (void)n_in; (void)out_size; (void)ws_size;
    const float* dtm    = (const float*)d_in[0];
    const float* demand = (const float*)d_in[1];
    const int*   routes = (const int*)d_in[2];
    float* out  = (float*)d_out;
    float* dist = (float*)d_ws;           // BNN floats
    float* hops = dist + BNN;             // BNN floats
    float* acc  = hops + BNN;             // 256 floats

    k_init  <<<BNN/256, 256, 0, stream>>>(dist, acc);
    k_routes<<<BB*RR,    64, 0, stream>>>(dtm, routes, dist, acc);
    k_fwinit<<<BNN/256, 256, 0, stream>>>(dist, hops);
    for (int kb = 0; kb < NBLK; kb++){
        k_fw_diag<<<BB,         256, 0, stream>>>(dist, hops, kb);
        k_fw_mp  <<<dim3(6,BB), 256, 0, stream>>>(dist, hops, kb, 2);
        k_fw_mp  <<<dim3(9,BB), 256, 0, stream>>>(dist, hops, kb, 3);
    }
    k_epi  <<<dim3(64,BB), 256, 0, stream>>>(dist, hops, demand, out, acc);
    k_final<<<1, 64, 0, stream>>>(acc, out);
}

// Round 5
// 346.202 us; speedup vs baseline: 1.7148x; 1.0953x over previous
//
#include <hip/hip_runtime.h>

// Problem constants
#define BB 16
#define NL 256
#define RR 24
#define LL 32
#define NN (NL*NL)        // 65536
#define BNN (BB*NN)       // 1048576
#define TT 64             // FW tile
#define NBLK 4            // 256/64
#define TP 68             // padded LDS row stride: %4==0 (16B-aligned float4) and 68%32=4 bank spread

// Output layout (float32), reference return order.
#define O_TDT 0
#define O_RT  16
#define O_TAT 32
#define O_TD  96
#define O_UNS 112
#define O_TTR 128
#define O_TT  144
#define O_ND  1048720

static __device__ __forceinline__ void atomicMinF(float* a, float v){
    atomicMin((unsigned int*)a, __float_as_uint(v));  // ok for non-negative floats
}

// ---------------- init: dist = INF (float4), accumulators = 0 ----------------
__global__ void k_init(float4* __restrict__ dist4, float* __restrict__ acc){
    int idx = blockIdx.x*256 + threadIdx.x;
    float inf = __builtin_huge_valf();
    dist4[idx] = make_float4(inf, inf, inf, inf);
    if (blockIdx.x == 0) acc[threadIdx.x] = 0.f;   // 256 floats: 16b x 16 slots (slot 255 = epi counter)
}

// ---------------- route edges: one wave per (b,r) ----------------
__global__ void k_routes(const float* __restrict__ dtm, const int* __restrict__ routes,
                         float* __restrict__ dist, float* __restrict__ acc){
    int br = blockIdx.x; int b = br / RR, r = br % RR;
    int lane = threadIdx.x;
    __shared__ int   s[LL];
    __shared__ float lf[LL], lr[LL], cf[LL], cr[LL];
    if (lane < LL) s[lane] = routes[(b*RR + r)*LL + lane];
    __syncthreads();
    if (lane < LL-1){
        int a0 = s[lane], a1 = s[lane+1];
        const float* dt = dtm + b*NN;
        lf[lane] = dt[a0*NL + a1] + 60.0f;   // MEAN_STOP_TIME_S
        lr[lane] = dt[a1*NL + a0] + 60.0f;
    }
    __syncthreads();
    if (lane == 0){
        float af = 0.f, ar = 0.f;
        cf[0] = 0.f; cr[0] = 0.f;
        for (int l = 0; l < LL-1; l++){
            af += lf[l]; ar += lr[l];
            cf[l+1] = af; cr[l+1] = ar;
        }
        atomicAdd(&acc[b*16 + 1], af + ar);  // total_route_time
    }
    __syncthreads();
    for (int p = lane; p < LL*LL; p += 64){
        int i = p >> 5, j = p & 31;
        if (j > i){
            atomicMinF(&dist[b*NN + s[i]*NL + s[j]], cf[j] - cf[i]); // fwd
            atomicMinF(&dist[b*NN + s[j]*NL + s[i]], cr[j] - cr[i]); // rev
        }
    }
}

// ---------------- FW phase 1: closure of the 64x64 diagonal tile --------------
// Kleene recursion, sub-tile 16. p1' in-wave shfl; p2'/p3' full-range static-
// offset float4 LDS (band updates idempotent because sub-diag is closed).
// dofix: apply FW-init transform (diag d=0; h=finite&offdiag) during stage-in;
// hops global memory is NOT read when dofix (it is uninitialized at kb==0).
__global__ __launch_bounds__(256) void k_fw_diag(float* __restrict__ dist, float* __restrict__ hops,
                                                 int kb, int dofix){
    int b = blockIdx.x;
    int t = threadIdx.x;
    __shared__ float D[TT][TP], H[TT][TP];
    float* Dg = dist + b*NN + kb*TT*(NL+1);
    float* Hg = hops + b*NN + kb*TT*(NL+1);
    // stage in
    #pragma unroll
    for (int u = 0; u < 4; u++){
        int fid = u*256 + t;
        int row = fid >> 4, c4 = (fid & 15)*4;
        float4 v = *(const float4*)(Dg + row*NL + c4);
        float dv[4] = {v.x, v.y, v.z, v.w};
        float hv[4];
        if (dofix){
            #pragma unroll
            for (int e = 0; e < 4; e++){
                int col = c4 + e;
                hv[e] = (row != col && dv[e] < 1e37f) ? 1.f : 0.f;
                if (row == col) dv[e] = 0.f;
            }
        } else {
            float4 w = *(const float4*)(Hg + row*NL + c4);
            hv[0]=w.x; hv[1]=w.y; hv[2]=w.z; hv[3]=w.w;
        }
        #pragma unroll
        for (int e = 0; e < 4; e++){ D[row][c4+e] = dv[e]; H[row][c4+e] = hv[e]; }
    }
    __syncthreads();
    int ty = t >> 4, tx = t & 15;
    int r0 = ty*4, c0 = tx*4;
    for (int skb = 0; skb < 4; skb++){
        int s0 = skb*16;
        // ---- p1': wave 0 closes 16x16 diag sub-tile via shfl (no barriers).
        if (t < 64){
            int i = t >> 2, jg = t & 3;
            float md[4], mh[4];
            #pragma unroll
            for (int c = 0; c < 4; c++){
                md[c] = D[s0+i][s0+4*jg+c];
                mh[c] = H[s0+i][s0+4*jg+c];
            }
            #pragma unroll
            for (int k = 0; k < 16; k++){
                float rd[4], rh[4];
                #pragma unroll
                for (int c = 0; c < 4; c++){
                    rd[c] = __shfl(md[c], (k<<2)|jg);
                    rh[c] = __shfl(mh[c], (k<<2)|jg);
                }
                float cdv = __shfl(md[k&3], (i<<2)|(k>>2));
                float chv = __shfl(mh[k&3], (i<<2)|(k>>2));
                #pragma unroll
                for (int c = 0; c < 4; c++){
                    float alt = cdv + rd[c];
                    if (alt < md[c]){ md[c] = alt; mh[c] = chv + rh[c]; }
                }
            }
            #pragma unroll
            for (int c = 0; c < 4; c++){
                D[s0+i][s0+4*jg+c] = md[c];
                H[s0+i][s0+4*jg+c] = mh[c];
            }
        }
        __syncthreads();
        // ---- p2': row strip = band rows x ALL 64 cols (one float4/thread),
        //           col strip = ALL 64 rows x band cols (one float4/thread).
        // Static offsets; band-region updates idempotent (closed sub-diag).
        int ri  = s0 + ty;            // row-strip row (16 rows x 16 col-groups)
        int cr2 = t >> 2;             // col-strip row (64 rows x 4 col-groups)
        int cc  = s0 + (t & 3)*4;
        float rsd[4], rsh[4], csd[4], csh[4];
        {
            float4 v  = *(float4*)&D[ri][c0];   float4 w  = *(float4*)&H[ri][c0];
            rsd[0]=v.x; rsd[1]=v.y; rsd[2]=v.z; rsd[3]=v.w;
            rsh[0]=w.x; rsh[1]=w.y; rsh[2]=w.z; rsh[3]=w.w;
            float4 v2 = *(float4*)&D[cr2][cc];  float4 w2 = *(float4*)&H[cr2][cc];
            csd[0]=v2.x; csd[1]=v2.y; csd[2]=v2.z; csd[3]=v2.w;
            csh[0]=w2.x; csh[1]=w2.y; csh[2]=w2.z; csh[3]=w2.w;
        }
        #pragma unroll
        for (int k = 0; k < 16; k++){
            float ad = D[ri][s0+k],  ah = H[ri][s0+k];      // A*[band][k] (broadcast)
            float4 bd = *(float4*)&D[s0+k][c0];
            float4 bh = *(float4*)&H[s0+k][c0];
            float bdv[4]={bd.x,bd.y,bd.z,bd.w}, bhv[4]={bh.x,bh.y,bh.z,bh.w};
            #pragma unroll
            for (int e = 0; e < 4; e++){
                float alt = ad + bdv[e];
                if (alt < rsd[e]){ rsd[e] = alt; rsh[e] = ah + bhv[e]; }
            }
            float a2 = D[cr2][s0+k], a2h = H[cr2][s0+k];    // C0[r][k]
            float4 b2 = *(float4*)&D[s0+k][cc];             // A*[k][band] (broadcast)
            float4 b2h = *(float4*)&H[s0+k][cc];
            float b2v[4]={b2.x,b2.y,b2.z,b2.w}, b2hv[4]={b2h.x,b2h.y,b2h.z,b2h.w};
            #pragma unroll
            for (int e = 0; e < 4; e++){
                float alt = a2 + b2v[e];
                if (alt < csd[e]){ csd[e] = alt; csh[e] = a2h + b2hv[e]; }
            }
        }
        __syncthreads();   // all p2 reads done
        *(float4*)&D[ri][c0]  = make_float4(rsd[0],rsd[1],rsd[2],rsd[3]);
        *(float4*)&H[ri][c0]  = make_float4(rsh[0],rsh[1],rsh[2],rsh[3]);
        *(float4*)&D[cr2][cc] = make_float4(csd[0],csd[1],csd[2],csd[3]);
        *(float4*)&H[cr2][cc] = make_float4(csh[0],csh[1],csh[2],csh[3]);
        __syncthreads();
        // ---- p3': full 64x64, 4x4 per thread, barrier-free k loop
        float dd[4][4], hh[4][4];
        #pragma unroll
        for (int ii = 0; ii < 4; ii++){
            float4 v = *(float4*)&D[r0+ii][c0];
            float4 w = *(float4*)&H[r0+ii][c0];
            dd[ii][0]=v.x; dd[ii][1]=v.y; dd[ii][2]=v.z; dd[ii][3]=v.w;
            hh[ii][0]=w.x; hh[ii][1]=w.y; hh[ii][2]=w.z; hh[ii][3]=w.w;
        }
        #pragma unroll
        for (int k = 0; k < 16; k++){
            float ad[4], ah2[4];
            #pragma unroll
            for (int ii = 0; ii < 4; ii++){ ad[ii] = D[r0+ii][s0+k]; ah2[ii] = H[r0+ii][s0+k]; }
            float4 bv = *(float4*)&D[s0+k][c0];
            float4 bq = *(float4*)&H[s0+k][c0];
            float bdv[4]={bv.x,bv.y,bv.z,bv.w}, bhv[4]={bq.x,bq.y,bq.z,bq.w};
            #pragma unroll
            for (int ii = 0; ii < 4; ii++)
            #pragma unroll
            for (int jj = 0; jj < 4; jj++){
                float alt = ad[ii] + bdv[jj];
                if (alt < dd[ii][jj]){ dd[ii][jj] = alt; hh[ii][jj] = ah2[ii] + bhv[jj]; }
            }
        }
        __syncthreads();   // all p3 reads done
        #pragma unroll
        for (int ii = 0; ii < 4; ii++){
            *(float4*)&D[r0+ii][c0] = make_float4(dd[ii][0],dd[ii][1],dd[ii][2],dd[ii][3]);
            *(float4*)&H[r0+ii][c0] = make_float4(hh[ii][0],hh[ii][1],hh[ii][2],hh[ii][3]);
        }
        __syncthreads();
    }
    // stage out
    #pragma unroll
    for (int u = 0; u < 4; u++){
        int fid = u*256 + t;
        int row = fid >> 4, c4 = (fid & 15)*4;
        *(float4*)(Dg + row*NL + c4) = make_float4(D[row][c4+0],D[row][c4+1],D[row][c4+2],D[row][c4+3]);
        *(float4*)(Hg + row*NL + c4) = make_float4(H[row][c4+0],H[row][c4+1],H[row][c4+2],H[row][c4+3]);
    }
}

// ---------------- FW phases 2+3: min-plus product, barrier-free k-loop ------
// dst (ti,tj); A=(ti,kb); B=(kb,tj). dofix (kb==0): transform dst on load
// (and operand too when operand==dst, i.e. phase 2: fixA when tj==kb, fixB
// when ti==kb); hops global is unread wherever uninitialized.
__global__ __launch_bounds__(256) void k_fw_mp(float* __restrict__ dist, float* __restrict__ hops,
                                               int kb, int phase, int dofix){
    int b = blockIdx.y;
    int m = blockIdx.x;
    int ti, tj;
    if (phase == 2){
        bool isRow = (m < 3);
        int o  = isRow ? m : m-3;
        int ob = o + (o >= kb ? 1 : 0);
        ti = isRow ? kb : ob;
        tj = isRow ? ob : kb;
    } else {
        int pi = m/3, pj = m%3;
        ti = pi + (pi >= kb ? 1 : 0);
        tj = pj + (pj >= kb ? 1 : 0);
    }
    bool fixA = dofix && (tj == kb);
    bool fixB = dofix && (ti == kb);
    int t = threadIdx.x, ty = t >> 4, tx = t & 15;
    int r0 = ty*4, c0 = tx*4;
    float* Dg = dist + b*NN + ti*TT*NL + tj*TT;
    float* Hg = hops + b*NN + ti*TT*NL + tj*TT;
    const float* Ag  = dist + b*NN + ti*TT*NL + kb*TT;
    const float* AHg = hops + b*NN + ti*TT*NL + kb*TT;
    const float* Bg  = dist + b*NN + kb*TT*NL + tj*TT;
    const float* BHg = hops + b*NN + kb*TT*NL + tj*TT;
    __shared__ float AtD[TT][TT], AtH[TT][TT], BD[TT][TT], BH[TT][TT]; // 64 KB
    float d[4][4], h[4][4];
    #pragma unroll
    for (int ii = 0; ii < 4; ii++){
        float4 v = *(float4*)(Dg + (r0+ii)*NL + c0);
        float dv[4] = {v.x,v.y,v.z,v.w}, hv[4];
        if (dofix){
            #pragma unroll
            for (int e = 0; e < 4; e++){
                int gi = ti*TT + r0 + ii, gj = tj*TT + c0 + e;
                hv[e] = (gi != gj && dv[e] < 1e37f) ? 1.f : 0.f;
                if (gi == gj) dv[e] = 0.f;
            }
        } else {
            float4 w = *(float4*)(Hg + (r0+ii)*NL + c0);
            hv[0]=w.x; hv[1]=w.y; hv[2]=w.z; hv[3]=w.w;
        }
        #pragma unroll
        for (int e = 0; e < 4; e++){ d[ii][e] = dv[e]; h[ii][e] = hv[e]; }

        float4 a = *(const float4*)(Ag + (r0+ii)*NL + c0);
        float av[4] = {a.x,a.y,a.z,a.w}, qv[4];
        if (fixA){
            #pragma unroll
            for (int e = 0; e < 4; e++){
                int gi = ti*TT + r0 + ii, gj = kb*TT + c0 + e;
                qv[e] = (gi != gj && av[e] < 1e37f) ? 1.f : 0.f;
                if (gi == gj) av[e] = 0.f;
            }
        } else {
            float4 q = *(const float4*)(AHg + (r0+ii)*NL + c0);
            qv[0]=q.x; qv[1]=q.y; qv[2]=q.z; qv[3]=q.w;
        }
        #pragma unroll
        for (int e = 0; e < 4; e++){ AtD[c0+e][r0+ii] = av[e]; AtH[c0+e][r0+ii] = qv[e]; }

        float4 bb = *(const float4*)(Bg + (r0+ii)*NL + c0);
        float bv[4] = {bb.x,bb.y,bb.z,bb.w}, qb[4];
        if (fixB){
            #pragma unroll
            for (int e = 0; e < 4; e++){
                int gi = kb*TT + r0 + ii, gj = tj*TT + c0 + e;
                qb[e] = (gi != gj && bv[e] < 1e37f) ? 1.f : 0.f;
                if (gi == gj) bv[e] = 0.f;
            }
        } else {
            float4 q = *(const float4*)(BHg + (r0+ii)*NL + c0);
            qb[0]=q.x; qb[1]=q.y; qb[2]=q.z; qb[3]=q.w;
        }
        #pragma unroll
        for (int e = 0; e < 4; e++){ BD[r0+ii][c0+e] = bv[e]; BH[r0+ii][c0+e] = qb[e]; }
    }
    __syncthreads();
    #pragma unroll 4
    for (int k = 0; k < TT; k++){
        float4 av = *(float4*)&AtD[k][r0];
        float4 aq = *(float4*)&AtH[k][r0];
        float4 bv = *(float4*)&BD[k][c0];
        float4 bq = *(float4*)&BH[k][c0];
        float a[4]={av.x,av.y,av.z,av.w}, ah[4]={aq.x,aq.y,aq.z,aq.w};
        float bb_[4]={bv.x,bv.y,bv.z,bv.w}, bh[4]={bq.x,bq.y,bq.z,bq.w};
        #pragma unroll
        for (int ii=0;ii<4;ii++)
        #pragma unroll
        for (int jj=0;jj<4;jj++){
            float alt = a[ii] + bb_[jj];
            if (alt < d[ii][jj]){ d[ii][jj]=alt; h[ii][jj]=ah[ii]+bh[jj]; }
        }
    }
    #pragma unroll
    for (int ii = 0; ii < 4; ii++){
        *(float4*)(Dg + (r0+ii)*NL + c0) = make_float4(d[ii][0],d[ii][1],d[ii][2],d[ii][3]);
        *(float4*)(Hg + (r0+ii)*NL + c0) = make_float4(h[ii][0],h[ii][1],h[ii][2],h[ii][3]);
    }
}

// ---------------- epilogue: trip_times + reductions + fused finalize ----------
__global__ __launch_bounds__(256) void k_epi(const float* __restrict__ dist,
        const float* __restrict__ hops, const float* __restrict__ demand,
        float* __restrict__ out, float* __restrict__ acc){
    int b = blockIdx.y;
    int base = b*NN + blockIdx.x*1024 + threadIdx.x;
    float s0=0,s1=0,s2=0,s3=0,s4=0,s5=0,s6=0,s7=0,s8=0;
    #pragma unroll
    for (int u = 0; u < 4; u++){
        int idx = base + u*256;
        float d = dist[idx], h = hops[idx], dm = demand[idx];
        bool np = !(d < 1e37f);
        float pl = np ? 0.f : h + 1.f;
        float tr = (pl == 0.f) ? 0.f : pl - 2.f;
        float tt = np ? 0.f : d + tr*300.f;   // AVG_TRANSFER_WAIT_TIME_S
        out[O_TT + idx] = tt;
        s0 += dm*tt;
        s1 += dm*tr;
        s2 += np ? dm : 0.f;
        s3 += dm;
        s4 += (np && dm > 0.f) ? 1.f : 0.f;
        s5 += (tr == 0.f) ? dm : 0.f;
        s6 += (tr == 1.f) ? dm : 0.f;
        s7 += (tr == 2.f) ? dm : 0.f;
        s8 += (tr > 2.f) ? dm : 0.f;
    }
    #define RED(x) { x += __shfl_down(x,32); x += __shfl_down(x,16); x += __shfl_down(x,8); \
                     x += __shfl_down(x,4);  x += __shfl_down(x,2);  x += __shfl_down(x,1); }
    RED(s0) RED(s1) RED(s2) RED(s3) RED(s4) RED(s5) RED(s6) RED(s7) RED(s8)
    __shared__ float red[4][9];
    int w = threadIdx.x >> 6;
    if ((threadIdx.x & 63) == 0){
        red[w][0]=s0; red[w][1]=s1; red[w][2]=s2; red[w][3]=s3; red[w][4]=s4;
        red[w][5]=s5; red[w][6]=s6; red[w][7]=s7; red[w][8]=s8;
    }
    __syncthreads();
    if (threadIdx.x < 9){
        float v = red[0][threadIdx.x] + red[1][threadIdx.x]
                + red[2][threadIdx.x] + red[3][threadIdx.x];
        // acc slots: 0 tdt, 1 rt, 2 ttrans, 3 uns, 4 tdem, 5 ndis, 6 b0, 7 b1, 8 b2, 9 bun
        int slot = (threadIdx.x == 0) ? 0 : threadIdx.x + 1;
        atomicAdd(&acc[b*16 + slot], v);
    }
    // fused finalize: last of the 1024 blocks writes the scalar outputs
    __syncthreads();                       // drain this block's atomics (barrier implies vmcnt(0))
    __shared__ int isLast;
    if (threadIdx.x == 0){
        unsigned prev = atomicAdd((unsigned int*)(acc + 255), 1u);
        isLast = (prev == 1023u) ? 1 : 0;
    }
    __syncthreads();
    if (isLast && threadIdx.x < BB){
        int bb = threadIdx.x;
        float a[10];
        #pragma unroll
        for (int s = 0; s < 10; s++) a[s] = atomicAdd(&acc[bb*16 + s], 0.f);  // coherent read
        out[O_TDT + bb] = a[0];
        out[O_RT  + bb] = a[1];
        out[O_TAT + 4*bb + 0] = a[6];
        out[O_TAT + 4*bb + 1] = a[7];
        out[O_TAT + 4*bb + 2] = a[8];
        out[O_TAT + 4*bb + 3] = a[9] + a[3];
        out[O_TD  + bb] = a[4];
        out[O_UNS + bb] = a[3];
        out[O_TTR + bb] = a[2];
        out[O_ND  + bb] = a[5];
    }
}

extern "C" void kernel_launch(void* const* d_in, const int* in_sizes, int n_in,
                              void* d_out, int out_size, void* d_ws, size_t ws_size,
                              hipStream_t stream){
    (void)in_sizes; (void)n_in; (void)out_size; (void)ws_size;
    const float* dtm    = (const float*)d_in[0];
    const float* demand = (const float*)d_in[1];
    const int*   routes = (const int*)d_in[2];
    float* out  = (float*)d_out;
    float* dist = (float*)d_ws;           // BNN floats
    float* hops = dist + BNN;             // BNN floats
    float* acc  = hops + BNN;             // 256 floats (incl. counter at [255])

    k_init  <<<BNN/1024, 256, 0, stream>>>((float4*)dist, acc);
    k_routes<<<BB*RR,     64, 0, stream>>>(dtm, routes, dist, acc);
    for (int kb = 0; kb < NBLK; kb++){
        int fix = (kb == 0) ? 1 : 0;
        k_fw_diag<<<BB,         256, 0, stream>>>(dist, hops, kb, fix);
        k_fw_mp  <<<dim3(6,BB), 256, 0, stream>>>(dist, hops, kb, 2, fix);
        k_fw_mp  <<<dim3(9,BB), 256, 0, stream>>>(dist, hops, kb, 3, fix);
    }
    k_epi  <<<dim3(64,BB), 256, 0, stream>>>(dist, hops, demand, out, acc);
}

// Round 6
// 299.949 us; speedup vs baseline: 1.9792x; 1.1542x over previous
//
#include <hip/hip_runtime.h>

// Problem constants
#define BB 16
#define NL 256
#define RR 24
#define LL 32
#define NN (NL*NL)        // 65536
#define BNN (BB*NN)       // 1048576
#define TT 64             // FW tile
#define NBLK 4            // 256/64
#define TP 68             // padded LDS row stride (16B-aligned, bank-spread)

// Output layout (float32), reference return order.
#define O_TDT 0
#define O_RT  16
#define O_TAT 32
#define O_TD  96
#define O_UNS 112
#define O_TTR 128
#define O_TT  144
#define O_ND  1048720

static __device__ __forceinline__ void atomicMinF(float* a, float v){
    atomicMin((unsigned int*)a, __float_as_uint(v));  // ok for non-negative floats
}

// ---------------- init: dist = INF (float4), accumulators = 0 ----------------
__global__ __launch_bounds__(1024) void k_init(float4* __restrict__ dist4, float* __restrict__ acc){
    int idx = blockIdx.x*1024 + threadIdx.x;
    float inf = __builtin_huge_valf();
    dist4[idx] = make_float4(inf, inf, inf, inf);
    if (blockIdx.x == 0 && threadIdx.x < 256) acc[threadIdx.x] = 0.f;
}

// ---------------- route edges: one wave per (b,r) ----------------
__global__ void k_routes(const float* __restrict__ dtm, const int* __restrict__ routes,
                         float* __restrict__ dist, float* __restrict__ acc){
    int br = blockIdx.x; int b = br / RR, r = br % RR;
    int lane = threadIdx.x;
    __shared__ int   s[LL];
    __shared__ float lf[LL], lr[LL], cf[LL], cr[LL];
    if (lane < LL) s[lane] = routes[(b*RR + r)*LL + lane];
    __syncthreads();
    if (lane < LL-1){
        int a0 = s[lane], a1 = s[lane+1];
        const float* dt = dtm + b*NN;
        lf[lane] = dt[a0*NL + a1] + 60.0f;   // MEAN_STOP_TIME_S
        lr[lane] = dt[a1*NL + a0] + 60.0f;
    }
    __syncthreads();
    if (lane == 0){
        float af = 0.f, ar = 0.f;
        cf[0] = 0.f; cr[0] = 0.f;
        for (int l = 0; l < LL-1; l++){
            af += lf[l]; ar += lr[l];
            cf[l+1] = af; cr[l+1] = ar;
        }
        atomicAdd(&acc[b*16 + 1], af + ar);  // total_route_time
    }
    __syncthreads();
    for (int p = lane; p < LL*LL; p += 64){
        int i = p >> 5, j = p & 31;
        if (j > i){
            atomicMinF(&dist[b*NN + s[i]*NL + s[j]], cf[j] - cf[i]); // fwd
            atomicMinF(&dist[b*NN + s[j]*NL + s[i]], cr[j] - cr[i]); // rev
        }
    }
}

// ---------------- FW phase 1: closure of 64x64 diagonal tile, 1024 threads ----
// Kleene recursion, sub-tile 16. p1' in-wave shfl (wave 0); p2' one row-strip
// element + one col-strip element per thread; p3' one 1x4 float4 slice/thread.
// dofix: apply FW-init transform on stage-in (hops global unread at kb==0).
__global__ __launch_bounds__(1024) void k_fw_diag(float* __restrict__ dist, float* __restrict__ hops,
                                                  int kb, int dofix){
    int b = blockIdx.x;
    int t = threadIdx.x;
    __shared__ float D[TT][TP], H[TT][TP];
    float* Dg = dist + b*NN + kb*TT*(NL+1);
    float* Hg = hops + b*NN + kb*TT*(NL+1);
    int row = t >> 4, c4 = (t & 15)*4;     // one float4 per thread
    {
        float4 v = *(const float4*)(Dg + row*NL + c4);
        float dv[4] = {v.x, v.y, v.z, v.w};
        float hv[4];
        if (dofix){
            #pragma unroll
            for (int e = 0; e < 4; e++){
                int col = c4 + e;
                hv[e] = (row != col && dv[e] < 1e37f) ? 1.f : 0.f;
                if (row == col) dv[e] = 0.f;
            }
        } else {
            float4 w = *(const float4*)(Hg + row*NL + c4);
            hv[0]=w.x; hv[1]=w.y; hv[2]=w.z; hv[3]=w.w;
        }
        #pragma unroll
        for (int e = 0; e < 4; e++){ D[row][c4+e] = dv[e]; H[row][c4+e] = hv[e]; }
    }
    __syncthreads();
    for (int skb = 0; skb < 4; skb++){
        int s0 = skb*16;
        // ---- p1': wave 0 closes 16x16 diag sub-tile via shfl (no barriers).
        if (t < 64){
            int i = t >> 2, jg = t & 3;
            float md[4], mh[4];
            #pragma unroll
            for (int c = 0; c < 4; c++){
                md[c] = D[s0+i][s0+4*jg+c];
                mh[c] = H[s0+i][s0+4*jg+c];
            }
            #pragma unroll
            for (int k = 0; k < 16; k++){
                float rd[4], rh[4];
                #pragma unroll
                for (int c = 0; c < 4; c++){
                    rd[c] = __shfl(md[c], (k<<2)|jg);
                    rh[c] = __shfl(mh[c], (k<<2)|jg);
                }
                float cdv = __shfl(md[k&3], (i<<2)|(k>>2));
                float chv = __shfl(mh[k&3], (i<<2)|(k>>2));
                #pragma unroll
                for (int c = 0; c < 4; c++){
                    float alt = cdv + rd[c];
                    if (alt < md[c]){ md[c] = alt; mh[c] = chv + rh[c]; }
                }
            }
            #pragma unroll
            for (int c = 0; c < 4; c++){
                D[s0+i][s0+4*jg+c] = md[c];
                H[s0+i][s0+4*jg+c] = mh[c];
            }
        }
        __syncthreads();
        // ---- p2': row strip (16 band rows x 64 cols) + col strip (64 rows x
        // 16 band cols), one element of each per thread. Band-square overlap
        // computes identical candidates in both -> benign same-value race.
        int rr = s0 + (t >> 6);        // row-strip row (wave-uniform)
        int ca = t & 63;               // row-strip col
        int cb = s0 + (t & 15);        // col-strip col
        float rsd = D[rr][ca],  rsh = H[rr][ca];
        float csd = D[row][cb], csh = H[row][cb];
        #pragma unroll
        for (int k = 0; k < 16; k++){
            float ad = D[rr][s0+k],  ah  = H[rr][s0+k];   // A*[band][k] broadcast
            float bd = D[s0+k][ca],  bh  = H[s0+k][ca];
            float alt = ad + bd;
            if (alt < rsd){ rsd = alt; rsh = ah + bh; }
            float a2 = D[row][s0+k], a2h = H[row][s0+k];  // C0[r][k]
            float b2 = D[s0+k][cb],  b2h = H[s0+k][cb];   // A*[k][band] broadcast
            float alt2 = a2 + b2;
            if (alt2 < csd){ csd = alt2; csh = a2h + b2h; }
        }
        __syncthreads();   // all p2' reads done
        D[rr][ca]  = rsd;  H[rr][ca]  = rsh;
        D[row][cb] = csd;  H[row][cb] = csh;
        __syncthreads();
        // ---- p3': full 64x64, 1x4 per thread, barrier-free k loop
        float dd[4], hh[4];
        {
            float4 v = *(float4*)&D[row][c4];
            float4 w = *(float4*)&H[row][c4];
            dd[0]=v.x; dd[1]=v.y; dd[2]=v.z; dd[3]=v.w;
            hh[0]=w.x; hh[1]=w.y; hh[2]=w.z; hh[3]=w.w;
        }
        #pragma unroll
        for (int k = 0; k < 16; k++){
            float ad = D[row][s0+k], ah2 = H[row][s0+k];
            float4 bv = *(float4*)&D[s0+k][c4];
            float4 bq = *(float4*)&H[s0+k][c4];
            float bdv[4]={bv.x,bv.y,bv.z,bv.w}, bhv[4]={bq.x,bq.y,bq.z,bq.w};
            #pragma unroll
            for (int jj = 0; jj < 4; jj++){
                float alt = ad + bdv[jj];
                if (alt < dd[jj]){ dd[jj] = alt; hh[jj] = ah2 + bhv[jj]; }
            }
        }
        __syncthreads();   // all p3' reads done
        *(float4*)&D[row][c4] = make_float4(dd[0],dd[1],dd[2],dd[3]);
        *(float4*)&H[row][c4] = make_float4(hh[0],hh[1],hh[2],hh[3]);
        __syncthreads();
    }
    // stage out
    *(float4*)(Dg + row*NL + c4) = make_float4(D[row][c4+0],D[row][c4+1],D[row][c4+2],D[row][c4+3]);
    *(float4*)(Hg + row*NL + c4) = make_float4(H[row][c4+0],H[row][c4+1],H[row][c4+2],H[row][c4+3]);
}

// ---------------- FW phases 2+3: min-plus product, 1024 threads ----------------
// dst (ti,tj); A=(ti,kb); B=(kb,tj). Each thread owns one 1x4 slice (row,c4).
// dofix (kb==0): FW-init transform on load where hops is uninitialized.
__global__ __launch_bounds__(1024) void k_fw_mp(float* __restrict__ dist, float* __restrict__ hops,
                                                int kb, int phase, int dofix){
    int b = blockIdx.y;
    int m = blockIdx.x;
    int ti, tj;
    if (phase == 2){
        bool isRow = (m < 3);
        int o  = isRow ? m : m-3;
        int ob = o + (o >= kb ? 1 : 0);
        ti = isRow ? kb : ob;
        tj = isRow ? ob : kb;
    } else {
        int pi = m/3, pj = m%3;
        ti = pi + (pi >= kb ? 1 : 0);
        tj = pj + (pj >= kb ? 1 : 0);
    }
    bool fixA = dofix && (tj == kb);
    bool fixB = dofix && (ti == kb);
    int t = threadIdx.x;
    int row = t >> 4, c4 = (t & 15)*4;
    float* Dg = dist + b*NN + ti*TT*NL + tj*TT;
    float* Hg = hops + b*NN + ti*TT*NL + tj*TT;
    const float* Ag  = dist + b*NN + ti*TT*NL + kb*TT;
    const float* AHg = hops + b*NN + ti*TT*NL + kb*TT;
    const float* Bg  = dist + b*NN + kb*TT*NL + tj*TT;
    const float* BHg = hops + b*NN + kb*TT*NL + tj*TT;
    __shared__ float AtD[TT][TT], AtH[TT][TT], BD[TT][TT], BH[TT][TT]; // 64 KB
    float d[4], h[4];
    {
        float4 v = *(float4*)(Dg + row*NL + c4);
        float dv[4] = {v.x,v.y,v.z,v.w}, hv[4];
        if (dofix){
            #pragma unroll
            for (int e = 0; e < 4; e++){
                int gi = ti*TT + row, gj = tj*TT + c4 + e;
                hv[e] = (gi != gj && dv[e] < 1e37f) ? 1.f : 0.f;
                if (gi == gj) dv[e] = 0.f;
            }
        } else {
            float4 w = *(float4*)(Hg + row*NL + c4);
            hv[0]=w.x; hv[1]=w.y; hv[2]=w.z; hv[3]=w.w;
        }
        #pragma unroll
        for (int e = 0; e < 4; e++){ d[e] = dv[e]; h[e] = hv[e]; }

        float4 a = *(const float4*)(Ag + row*NL + c4);
        float av[4] = {a.x,a.y,a.z,a.w}, qv[4];
        if (fixA){
            #pragma unroll
            for (int e = 0; e < 4; e++){
                int gi = ti*TT + row, gj = kb*TT + c4 + e;
                qv[e] = (gi != gj && av[e] < 1e37f) ? 1.f : 0.f;
                if (gi == gj) av[e] = 0.f;
            }
        } else {
            float4 q = *(const float4*)(AHg + row*NL + c4);
            qv[0]=q.x; qv[1]=q.y; qv[2]=q.z; qv[3]=q.w;
        }
        #pragma unroll
        for (int e = 0; e < 4; e++){ AtD[c4+e][row] = av[e]; AtH[c4+e][row] = qv[e]; }

        float4 bb = *(const float4*)(Bg + row*NL + c4);
        float bv[4] = {bb.x,bb.y,bb.z,bb.w}, qb[4];
        if (fixB){
            #pragma unroll
            for (int e = 0; e < 4; e++){
                int gi = kb*TT + row, gj = tj*TT + c4 + e;
                qb[e] = (gi != gj && bv[e] < 1e37f) ? 1.f : 0.f;
                if (gi == gj) bv[e] = 0.f;
            }
        } else {
            float4 q = *(const float4*)(BHg + row*NL + c4);
            qb[0]=q.x; qb[1]=q.y; qb[2]=q.z; qb[3]=q.w;
        }
        *(float4*)&BD[row][c4] = make_float4(qb[0]*0.f+bv[0],bv[1],bv[2],bv[3]);
        *(float4*)&BH[row][c4] = make_float4(qb[0],qb[1],qb[2],qb[3]);
    }
    __syncthreads();
    // k-loop: A*[row][k] = AtD[k][row] (4 distinct rows/wave -> conflict-free
    // distinct banks, x16 broadcast); B[k][c4..] float4.
    #pragma unroll 8
    for (int k = 0; k < TT; k++){
        float ad = AtD[k][row], ah = AtH[k][row];
        float4 bv = *(float4*)&BD[k][c4];
        float4 bq = *(float4*)&BH[k][c4];
        float bdv[4]={bv.x,bv.y,bv.z,bv.w}, bhv[4]={bq.x,bq.y,bq.z,bq.w};
        #pragma unroll
        for (int jj = 0; jj < 4; jj++){
            float alt = ad + bdv[jj];
            if (alt < d[jj]){ d[jj] = alt; h[jj] = ah + bhv[jj]; }
        }
    }
    *(float4*)(Dg + row*NL + c4) = make_float4(d[0],d[1],d[2],d[3]);
    *(float4*)(Hg + row*NL + c4) = make_float4(h[0],h[1],h[2],h[3]);
}

// ---------------- epilogue: trip_times + reductions + fused finalize ----------
__global__ __launch_bounds__(1024) void k_epi(const float4* __restrict__ dist4,
        const float4* __restrict__ hops4, const float4* __restrict__ demand4,
        float* __restrict__ out, float* __restrict__ acc){
    int b = blockIdx.y;
    int fid = (b*NN >> 2) + blockIdx.x*1024 + threadIdx.x;   // float4 index
    float4 dv = dist4[fid], hv = hops4[fid], mv = demand4[fid];
    float ds[4] = {dv.x,dv.y,dv.z,dv.w};
    float hs[4] = {hv.x,hv.y,hv.z,hv.w};
    float ms[4] = {mv.x,mv.y,mv.z,mv.w};
    float s0=0,s1=0,s2=0,s3=0,s4=0,s5=0,s6=0,s7=0,s8=0;
    float tts[4];
    #pragma unroll
    for (int e = 0; e < 4; e++){
        float d = ds[e], h = hs[e], dm = ms[e];
        bool np = !(d < 1e37f);
        float pl = np ? 0.f : h + 1.f;
        float tr = (pl == 0.f) ? 0.f : pl - 2.f;
        float tt = np ? 0.f : d + tr*300.f;   // AVG_TRANSFER_WAIT_TIME_S
        tts[e] = tt;
        s0 += dm*tt;
        s1 += dm*tr;
        s2 += np ? dm : 0.f;
        s3 += dm;
        s4 += (np && dm > 0.f) ? 1.f : 0.f;
        s5 += (tr == 0.f) ? dm : 0.f;
        s6 += (tr == 1.f) ? dm : 0.f;
        s7 += (tr == 2.f) ? dm : 0.f;
        s8 += (tr > 2.f) ? dm : 0.f;
    }
    ((float4*)(out + O_TT))[fid] = make_float4(tts[0],tts[1],tts[2],tts[3]);
    #define RED(x) { x += __shfl_down(x,32); x += __shfl_down(x,16); x += __shfl_down(x,8); \
                     x += __shfl_down(x,4);  x += __shfl_down(x,2);  x += __shfl_down(x,1); }
    RED(s0) RED(s1) RED(s2) RED(s3) RED(s4) RED(s5) RED(s6) RED(s7) RED(s8)
    __shared__ float red[16][9];
    int w = threadIdx.x >> 6;
    if ((threadIdx.x & 63) == 0){
        red[w][0]=s0; red[w][1]=s1; red[w][2]=s2; red[w][3]=s3; red[w][4]=s4;
        red[w][5]=s5; red[w][6]=s6; red[w][7]=s7; red[w][8]=s8;
    }
    __syncthreads();
    if (threadIdx.x < 9){
        float v = 0.f;
        #pragma unroll
        for (int ww = 0; ww < 16; ww++) v += red[ww][threadIdx.x];
        // acc slots: 0 tdt, 1 rt, 2 ttrans, 3 uns, 4 tdem, 5 ndis, 6 b0, 7 b1, 8 b2, 9 bun
        int slot = (threadIdx.x == 0) ? 0 : threadIdx.x + 1;
        atomicAdd(&acc[b*16 + slot], v);
    }
    __syncthreads();
    __shared__ int isLast;
    if (threadIdx.x == 0){
        unsigned prev = atomicAdd((unsigned int*)(acc + 255), 1u);
        isLast = (prev == 255u) ? 1 : 0;   // 16x16 = 256 blocks
    }
    __syncthreads();
    if (isLast && threadIdx.x < BB){
        int bb = threadIdx.x;
        float a[10];
        #pragma unroll
        for (int s = 0; s < 10; s++) a[s] = atomicAdd(&acc[bb*16 + s], 0.f);  // coherent read
        out[O_TDT + bb] = a[0];
        out[O_RT  + bb] = a[1];
        out[O_TAT + 4*bb + 0] = a[6];
        out[O_TAT + 4*bb + 1] = a[7];
        out[O_TAT + 4*bb + 2] = a[8];
        out[O_TAT + 4*bb + 3] = a[9] + a[3];
        out[O_TD  + bb] = a[4];
        out[O_UNS + bb] = a[3];
        out[O_TTR + bb] = a[2];
        out[O_ND  + bb] = a[5];
    }
}

extern "C" void kernel_launch(void* const* d_in, const int* in_sizes, int n_in,
                              void* d_out, int out_size, void* d_ws, size_t ws_size,
                              hipStream_t stream){
    (void)in_sizes; (void)n_in; (void)out_size; (void)ws_size;
    const float* dtm    = (const float*)d_in[0];
    const float* demand = (const float*)d_in[1];
    const int*   routes = (const int*)d_in[2];
    float* out  = (float*)d_out;
    float* dist = (float*)d_ws;           // BNN floats
    float* hops = dist + BNN;             // BNN floats
    float* acc  = hops + BNN;             // 256 floats (incl. counter at [255])

    k_init  <<<BNN/4096, 1024, 0, stream>>>((float4*)dist, acc);
    k_routes<<<BB*RR,      64, 0, stream>>>(dtm, routes, dist, acc);
    for (int kb = 0; kb < NBLK; kb++){
        int fix = (kb == 0) ? 1 : 0;
        k_fw_diag<<<BB,         1024, 0, stream>>>(dist, hops, kb, fix);
        k_fw_mp  <<<dim3(6,BB), 1024, 0, stream>>>(dist, hops, kb, 2, fix);
        k_fw_mp  <<<dim3(9,BB), 1024, 0, stream>>>(dist, hops, kb, 3, fix);
    }
    k_epi<<<dim3(16,BB), 1024, 0, stream>>>((const float4*)dist, (const float4*)hops,
                                            (const float4*)demand, out, acc);
}